// Round 3
// baseline (771.078 us; speedup 1.0000x reference)
//
#include <hip/hip_runtime.h>
#include <hip/hip_bf16.h>

#define N_ROWS 200000
#define NTILES 3125
#define NGRAPH 64
#define GRID 512
#define SSCALE 1.6666666666666667f

typedef __attribute__((ext_vector_type(8))) short short8;   // 8 bf16 (4 VGPRs)
typedef __attribute__((ext_vector_type(4))) float f32x4;    // MFMA C/D frag

__device__ __forceinline__ unsigned short f2bf(float f) {
    unsigned int u = __float_as_uint(f);
    u = (u + 0x7fffu + ((u >> 16) & 1u)) >> 16;   // RNE
    return (unsigned short)u;
}
__device__ __forceinline__ float bf2f(unsigned short v) {
    return __uint_as_float(((unsigned int)v) << 16);
}
__device__ __forceinline__ float ssilu_f(float s) {
    return s / (1.0f + __expf(-s)) * SSCALE;
}

// ---- weight convert + transpose: W[256][256] f32 -> out[256][256] bf16 (N-major) ----
__global__ void cvt_transpose(const float* __restrict__ W, unsigned short* __restrict__ out) {
    int idx = blockIdx.x * 256 + threadIdx.x;
    int n = idx >> 8;
    int k = idx & 255;
    out[idx] = f2bf(W[k * 256 + n]);
}

// ---- vc[b][n] = bn1[n] + sum_k vx[b][k] * Wn1[256+k][n]  (exact f32) ----
__global__ void vc_kernel(const float* __restrict__ vx, const float* __restrict__ Wn1,
                          const float* __restrict__ bn1, float* __restrict__ vc) {
    __shared__ float vrow[256];
    int b = blockIdx.x, t = threadIdx.x;
    vrow[t] = vx[b * 256 + t];
    __syncthreads();
    float a = bn1[t];
    #pragma unroll 8
    for (int k = 0; k < 256; ++k) a = fmaf(vrow[k], Wn1[(256 + k) * 256 + t], a);
    vc[b * 256 + t] = a;
}

// ---- zero sums + per-graph counts (batch sorted) ----
__global__ void prep_kernel(const int* __restrict__ batch, float* __restrict__ sums,
                            int* __restrict__ counts) {
    int b = blockIdx.x, t = threadIdx.x;
    sums[b * 256 + t] = 0.0f;
    if (t == 0) {
        int lo = 0, hi = N_ROWS;
        while (lo < hi) { int m = (lo + hi) >> 1; if (batch[m] < b) lo = m + 1; else hi = m; }
        int lb = lo;
        lo = 0; hi = N_ROWS;
        while (lo < hi) { int m = (lo + hi) >> 1; if (batch[m] < b + 1) lo = m + 1; else hi = m; }
        counts[b] = lo - lb;
    }
}

// ---- main fused node-MLP kernel: persistent, double-buffered via register prefetch ----
__global__ __launch_bounds__(256, 2) void node_kernel(
    const float* __restrict__ x, const int* __restrict__ batch,
    const unsigned short* __restrict__ wnt1x,  // [256][256] bf16, x-half of Wn1, N-major
    const float* __restrict__ vc,              // [64][256] per-graph bias (incl bn1)
    const unsigned short* __restrict__ wnt2,   // [256][256] bf16, N-major
    const float* __restrict__ bn2,
    float* __restrict__ hout, float* __restrict__ sums)
{
    __shared__ unsigned short xa[64 * 256];   // x tile, bf16, swizzled
    __shared__ unsigned short hb[64 * 256];   // h1 tile, bf16, swizzled

    const int t = threadIdx.x;
    const int lane = t & 63;
    const int wave = t >> 6;
    const int lr = lane & 15;
    const int lg = lane >> 4;
    const int wcol = wave * 64;

    float4 vreg[16];
    int tile = blockIdx.x;
    {
        const float* xp = x + (size_t)tile * 16384;
        #pragma unroll
        for (int i = 0; i < 16; ++i)
            vreg[i] = *reinterpret_cast<const float4*>(xp + (t + i * 256) * 4);
    }

    while (tile < NTILES) {
        const int r0 = tile * 64;

        // ---- [A] cvt + write x tile into LDS (swizzled) ----
        #pragma unroll
        for (int i = 0; i < 16; ++i) {
            int flat = (t + i * 256) * 4;
            int row = flat >> 8, col = flat & 255;
            int e = ((row << 8) + col) ^ ((row & 7) << 3);
            ushort4 u;
            u.x = f2bf(vreg[i].x); u.y = f2bf(vreg[i].y);
            u.z = f2bf(vreg[i].z); u.w = f2bf(vreg[i].w);
            *reinterpret_cast<ushort4*>(&xa[e]) = u;
        }
        __syncthreads();

        // ---- GEMM1: [64x256] @ [256x256] ----
        f32x4 zero4 = {0.f, 0.f, 0.f, 0.f};
        f32x4 acc[4][4];
        #pragma unroll
        for (int m = 0; m < 4; ++m)
            #pragma unroll
            for (int n = 0; n < 4; ++n) acc[m][n] = zero4;

        #pragma unroll
        for (int kk = 0; kk < 8; ++kk) {
            int kc = kk * 32 + lg * 8;
            short8 af[4], bfr[4];
            #pragma unroll
            for (int m = 0; m < 4; ++m) {
                int row = m * 16 + lr;
                int e = ((row << 8) + kc) ^ ((row & 7) << 3);
                af[m] = *reinterpret_cast<const short8*>(&xa[e]);
            }
            #pragma unroll
            for (int n = 0; n < 4; ++n)
                bfr[n] = *reinterpret_cast<const short8*>(&wnt1x[(wcol + n * 16 + lr) * 256 + kc]);
            #pragma unroll
            for (int m = 0; m < 4; ++m)
                #pragma unroll
                for (int n = 0; n < 4; ++n)
                    acc[m][n] = __builtin_amdgcn_mfma_f32_16x16x32_bf16(af[m], bfr[n], acc[m][n], 0, 0, 0);
        }

        // ---- h1 = ssilu(acc + vc[batch[row]][col]) -> hb ----
        #pragma unroll
        for (int n = 0; n < 4; ++n) {
            int col = wcol + n * 16 + lr;
            #pragma unroll
            for (int m = 0; m < 4; ++m) {
                #pragma unroll
                for (int r = 0; r < 4; ++r) {
                    int row = m * 16 + lg * 4 + r;
                    int b = batch[r0 + row];
                    float hv = ssilu_f(acc[m][n][r] + vc[b * 256 + col]);
                    int e = ((row << 8) + col) ^ ((row & 7) << 3);
                    hb[e] = f2bf(hv);
                }
            }
        }
        __syncthreads();

        // ---- prefetch next x tile into registers (latency hides under GEMM2+epilogue) ----
        int ntile = tile + GRID;
        if (ntile < NTILES) {
            const float* xp = x + (size_t)ntile * 16384;
            #pragma unroll
            for (int i = 0; i < 16; ++i)
                vreg[i] = *reinterpret_cast<const float4*>(xp + (t + i * 256) * 4);
        }

        // ---- GEMM2: [64x256] @ [256x256] ----
        f32x4 acc2[4][4];
        #pragma unroll
        for (int m = 0; m < 4; ++m)
            #pragma unroll
            for (int n = 0; n < 4; ++n) acc2[m][n] = zero4;

        #pragma unroll
        for (int kk = 0; kk < 8; ++kk) {
            int kc = kk * 32 + lg * 8;
            short8 af[4], bfr[4];
            #pragma unroll
            for (int m = 0; m < 4; ++m) {
                int row = m * 16 + lr;
                int e = ((row << 8) + kc) ^ ((row & 7) << 3);
                af[m] = *reinterpret_cast<const short8*>(&hb[e]);
            }
            #pragma unroll
            for (int n = 0; n < 4; ++n)
                bfr[n] = *reinterpret_cast<const short8*>(&wnt2[(wcol + n * 16 + lr) * 256 + kc]);
            #pragma unroll
            for (int m = 0; m < 4; ++m)
                #pragma unroll
                for (int n = 0; n < 4; ++n)
                    acc2[m][n] = __builtin_amdgcn_mfma_f32_16x16x32_bf16(af[m], bfr[n], acc2[m][n], 0, 0, 0);
        }

        // ---- epilogue: h = ssilu(acc2 + bn2) + x ; store + pooled sums ----
        const bool multi = (batch[r0] != batch[r0 + 63]);
        const int bfst = batch[r0];
        float ps[4] = {0.f, 0.f, 0.f, 0.f};

        #pragma unroll
        for (int n = 0; n < 4; ++n) {
            int col = wcol + n * 16 + lr;
            float bias = bn2[col];
            #pragma unroll
            for (int m = 0; m < 4; ++m) {
                #pragma unroll
                for (int r = 0; r < 4; ++r) {
                    int row = m * 16 + lg * 4 + r;
                    float hv = ssilu_f(acc2[m][n][r] + bias);
                    int e = ((row << 8) + col) ^ ((row & 7) << 3);
                    hv += bf2f(xa[e]);                       // residual (bf16 x)
                    hout[(size_t)(r0 + row) * 256 + col] = hv;
                    if (!multi) ps[n] += hv;
                    else atomicAdd(&sums[batch[r0 + row] * 256 + col], hv);
                }
            }
        }
        if (!multi) {
            #pragma unroll
            for (int n = 0; n < 4; ++n) {
                float p = ps[n];
                p += __shfl_xor(p, 16);
                p += __shfl_xor(p, 32);
                if (lane < 16) atomicAdd(&sums[bfst * 256 + wcol + n * 16 + lane], p);
            }
        }
        __syncthreads();   // protects xa (residual reads) and hb (GEMM2 reads) from next iter's writes
        tile = ntile;
    }
}

// ---- virtual-node MLP layer 1: v = ssilu(cat(pooled, vx) @ Wv1 + bv1) ----
__global__ void vmlp1(const float* __restrict__ sums, const int* __restrict__ counts,
                      const float* __restrict__ vx, const float* __restrict__ Wv1,
                      const float* __restrict__ bv1, float* __restrict__ v) {
    __shared__ float cat[512];
    int b = blockIdx.x, t = threadIdx.x;
    float cnt = fmaxf((float)counts[b], 1.0f);
    cat[t] = sums[b * 256 + t] / cnt;
    cat[t + 256] = vx[b * 256 + t];
    __syncthreads();
    float a = 0.f;
    #pragma unroll 8
    for (int k = 0; k < 512; ++k) a = fmaf(cat[k], Wv1[k * 256 + t], a);
    a += bv1[t];
    v[b * 256 + t] = ssilu_f(a);
}

// ---- virtual-node MLP layer 2: vx_new = ssilu(v @ Wv2 + bv2) ----
__global__ void vmlp2(const float* __restrict__ v, const float* __restrict__ Wv2,
                      const float* __restrict__ bv2, float* __restrict__ out) {
    __shared__ float rowv[256];
    int b = blockIdx.x, t = threadIdx.x;
    rowv[t] = v[b * 256 + t];
    __syncthreads();
    float a = 0.f;
    #pragma unroll 8
    for (int k = 0; k < 256; ++k) a = fmaf(rowv[k], Wv2[k * 256 + t], a);
    a += bv2[t];
    out[b * 256 + t] = ssilu_f(a);
}

extern "C" void kernel_launch(void* const* d_in, const int* in_sizes, int n_in,
                              void* d_out, int out_size, void* d_ws, size_t ws_size,
                              hipStream_t stream) {
    const float* x   = (const float*)d_in[0];
    const int*   batch = (const int*)d_in[1];
    const float* vx  = (const float*)d_in[2];
    const float* Wn1 = (const float*)d_in[3];
    const float* bn1 = (const float*)d_in[4];
    const float* Wn2 = (const float*)d_in[5];
    const float* bn2 = (const float*)d_in[6];
    const float* Wv1 = (const float*)d_in[7];
    const float* bv1 = (const float*)d_in[8];
    const float* Wv2 = (const float*)d_in[9];
    const float* bv2 = (const float*)d_in[10];

    float* hout = (float*)d_out;
    float* vout = hout + (size_t)N_ROWS * 256;   // also reused as v-scratch

    // ws layout — total 393,472 B
    char* ws = (char*)d_ws;
    unsigned short* wnt1x  = (unsigned short*)(ws);           // 256*256*2 = 131072
    unsigned short* wnt2   = (unsigned short*)(ws + 131072);  // 131072
    float*          vc     = (float*)(ws + 262144);           // 64*256*4  = 65536
    float*          sums   = (float*)(ws + 327680);           // 65536
    int*            counts = (int*)(ws + 393216);             // 256

    cvt_transpose<<<256, 256, 0, stream>>>(Wn1, wnt1x);   // x-half of Wn1 (rows 0..255)
    cvt_transpose<<<256, 256, 0, stream>>>(Wn2, wnt2);
    vc_kernel<<<NGRAPH, 256, 0, stream>>>(vx, Wn1, bn1, vc);
    prep_kernel<<<NGRAPH, 256, 0, stream>>>(batch, sums, counts);
    node_kernel<<<GRID, 256, 0, stream>>>(x, batch, wnt1x, vc, wnt2, bn2, hout, sums);
    vmlp1<<<NGRAPH, 256, 0, stream>>>(sums, counts, vx, Wv1, bv1, vout);
    vmlp2<<<NGRAPH, 256, 0, stream>>>(vout, Wv2, bv2, vout);
}

// Round 4
// 366.369 us; speedup vs baseline: 2.1046x; 2.1046x over previous
//
#include <hip/hip_runtime.h>
#include <hip/hip_bf16.h>

#define N_ROWS 200000
#define BM 32
#define NTILES 6250
#define NGRAPH 64
#define SSCALE 1.6666666666666667f

typedef __attribute__((ext_vector_type(8))) short short8;   // 8 bf16 (4 VGPRs)
typedef __attribute__((ext_vector_type(4))) float f32x4;    // MFMA C/D frag

__device__ __forceinline__ unsigned short f2bf(float f) {
    unsigned int u = __float_as_uint(f);
    u = (u + 0x7fffu + ((u >> 16) & 1u)) >> 16;   // RNE
    return (unsigned short)u;
}
__device__ __forceinline__ float bf2f(unsigned short v) {
    return __uint_as_float(((unsigned int)v) << 16);
}
__device__ __forceinline__ float ssilu_f(float s) {
    return s / (1.0f + __expf(-s)) * SSCALE;
}

// ---- weight convert + transpose: W[256][256] f32 -> out[256][256] bf16 (N-major) ----
__global__ void cvt_transpose(const float* __restrict__ W, unsigned short* __restrict__ out) {
    int idx = blockIdx.x * 256 + threadIdx.x;
    int n = idx >> 8;
    int k = idx & 255;
    out[idx] = f2bf(W[k * 256 + n]);
}

// ---- vc[b][n] = bn1[n] + sum_k vx[b][k] * Wn1[256+k][n]  (exact f32) ----
__global__ void vc_kernel(const float* __restrict__ vx, const float* __restrict__ Wn1,
                          const float* __restrict__ bn1, float* __restrict__ vc) {
    __shared__ float vrow[256];
    int b = blockIdx.x, t = threadIdx.x;
    vrow[t] = vx[b * 256 + t];
    __syncthreads();
    float a = bn1[t];
    #pragma unroll 8
    for (int k = 0; k < 256; ++k) a = fmaf(vrow[k], Wn1[(256 + k) * 256 + t], a);
    vc[b * 256 + t] = a;
}

// ---- zero sums + per-graph counts (batch sorted) ----
__global__ void prep_kernel(const int* __restrict__ batch, float* __restrict__ sums,
                            int* __restrict__ counts) {
    int b = blockIdx.x, t = threadIdx.x;
    sums[b * 256 + t] = 0.0f;
    if (t == 0) {
        int lo = 0, hi = N_ROWS;
        while (lo < hi) { int m = (lo + hi) >> 1; if (batch[m] < b) lo = m + 1; else hi = m; }
        int lb = lo;
        lo = 0; hi = N_ROWS;
        while (lo < hi) { int m = (lo + hi) >> 1; if (batch[m] < b + 1) lo = m + 1; else hi = m; }
        counts[b] = lo - lb;
    }
}

// ---- main fused node-MLP kernel: one 32-row tile per block, 4 blocks/CU ----
__global__ __launch_bounds__(256, 4) void node_kernel(
    const float* __restrict__ x, const int* __restrict__ batch,
    const unsigned short* __restrict__ wnt1x,  // [256][256] bf16, x-half of Wn1, N-major
    const float* __restrict__ vc,              // [64][256] per-graph bias (incl bn1)
    const unsigned short* __restrict__ wnt2,   // [256][256] bf16, N-major
    const float* __restrict__ bn2,
    float* __restrict__ hout, float* __restrict__ sums)
{
    __shared__ unsigned short xa[BM * 256];   // x tile, bf16, swizzled (16 KB)
    __shared__ unsigned short hb[BM * 256];   // h1 tile, bf16, swizzled (16 KB)

    const int t = threadIdx.x;
    const int lane = t & 63;
    const int wave = t >> 6;
    const int lr = lane & 15;
    const int lg = lane >> 4;
    const int wcol = wave * 64;
    const int r0 = blockIdx.x * BM;

    // ---- stage: x tile -> LDS bf16 (swizzled) ----
    #pragma unroll
    for (int i = 0; i < 8; ++i) {
        int flat = (t + i * 256) * 4;           // element in 32x256 tile
        int row = flat >> 8, col = flat & 255;
        float4 v = *reinterpret_cast<const float4*>(&x[(size_t)r0 * 256 + flat]);
        int e = ((row << 8) + col) ^ ((row & 7) << 3);
        ushort4 u;
        u.x = f2bf(v.x); u.y = f2bf(v.y); u.z = f2bf(v.z); u.w = f2bf(v.w);
        *reinterpret_cast<ushort4*>(&xa[e]) = u;
    }
    __syncthreads();

    // ---- GEMM1: [32x256] @ [256x256] ----
    f32x4 zero4 = {0.f, 0.f, 0.f, 0.f};
    f32x4 acc[2][4];
    #pragma unroll
    for (int m = 0; m < 2; ++m)
        #pragma unroll
        for (int n = 0; n < 4; ++n) acc[m][n] = zero4;

    #pragma unroll
    for (int kk = 0; kk < 8; ++kk) {
        int kc = kk * 32 + lg * 8;
        short8 af[2], bfr[4];
        #pragma unroll
        for (int m = 0; m < 2; ++m) {
            int row = m * 16 + lr;
            int e = ((row << 8) + kc) ^ ((row & 7) << 3);
            af[m] = *reinterpret_cast<const short8*>(&xa[e]);
        }
        #pragma unroll
        for (int n = 0; n < 4; ++n)
            bfr[n] = *reinterpret_cast<const short8*>(&wnt1x[(wcol + n * 16 + lr) * 256 + kc]);
        #pragma unroll
        for (int m = 0; m < 2; ++m)
            #pragma unroll
            for (int n = 0; n < 4; ++n)
                acc[m][n] = __builtin_amdgcn_mfma_f32_16x16x32_bf16(af[m], bfr[n], acc[m][n], 0, 0, 0);
    }

    // ---- h1 = ssilu(acc + vc[batch[row]][col]) -> hb ----
    const bool multi = (batch[r0] != batch[r0 + BM - 1]);
    const int b0 = batch[r0];
    float vcv[4];
    if (!multi) {
        #pragma unroll
        for (int n = 0; n < 4; ++n) vcv[n] = vc[b0 * 256 + wcol + n * 16 + lr];
    }

    #pragma unroll
    for (int n = 0; n < 4; ++n) {
        int col = wcol + n * 16 + lr;
        #pragma unroll
        for (int m = 0; m < 2; ++m) {
            #pragma unroll
            for (int r = 0; r < 4; ++r) {
                int row = m * 16 + lg * 4 + r;
                float bias = multi ? vc[batch[r0 + row] * 256 + col] : vcv[n];
                float hv = ssilu_f(acc[m][n][r] + bias);
                int e = ((row << 8) + col) ^ ((row & 7) << 3);
                hb[e] = f2bf(hv);
            }
        }
    }
    __syncthreads();

    // ---- GEMM2: [32x256] @ [256x256] ----
    f32x4 acc2[2][4];
    #pragma unroll
    for (int m = 0; m < 2; ++m)
        #pragma unroll
        for (int n = 0; n < 4; ++n) acc2[m][n] = zero4;

    #pragma unroll
    for (int kk = 0; kk < 8; ++kk) {
        int kc = kk * 32 + lg * 8;
        short8 af[2], bfr[4];
        #pragma unroll
        for (int m = 0; m < 2; ++m) {
            int row = m * 16 + lr;
            int e = ((row << 8) + kc) ^ ((row & 7) << 3);
            af[m] = *reinterpret_cast<const short8*>(&hb[e]);
        }
        #pragma unroll
        for (int n = 0; n < 4; ++n)
            bfr[n] = *reinterpret_cast<const short8*>(&wnt2[(wcol + n * 16 + lr) * 256 + kc]);
        #pragma unroll
        for (int m = 0; m < 2; ++m)
            #pragma unroll
            for (int n = 0; n < 4; ++n)
                acc2[m][n] = __builtin_amdgcn_mfma_f32_16x16x32_bf16(af[m], bfr[n], acc2[m][n], 0, 0, 0);
    }

    // ---- epilogue: h = ssilu(acc2 + bn2) + x ; store + pooled sums ----
    float ps[4] = {0.f, 0.f, 0.f, 0.f};

    #pragma unroll
    for (int n = 0; n < 4; ++n) {
        int col = wcol + n * 16 + lr;
        float bias = bn2[col];
        #pragma unroll
        for (int m = 0; m < 2; ++m) {
            #pragma unroll
            for (int r = 0; r < 4; ++r) {
                int row = m * 16 + lg * 4 + r;
                float hv = ssilu_f(acc2[m][n][r] + bias);
                int e = ((row << 8) + col) ^ ((row & 7) << 3);
                hv += bf2f(xa[e]);                       // residual (bf16 x)
                hout[(size_t)(r0 + row) * 256 + col] = hv;
                if (!multi) ps[n] += hv;
                else atomicAdd(&sums[batch[r0 + row] * 256 + col], hv);
            }
        }
    }
    if (!multi) {
        #pragma unroll
        for (int n = 0; n < 4; ++n) {
            float p = ps[n];
            p += __shfl_xor(p, 16);
            p += __shfl_xor(p, 32);
            if (lane < 16) atomicAdd(&sums[b0 * 256 + wcol + n * 16 + lane], p);
        }
    }
}

// ---- virtual-node MLP layer 1: v = ssilu(cat(pooled, vx) @ Wv1 + bv1) ----
__global__ void vmlp1(const float* __restrict__ sums, const int* __restrict__ counts,
                      const float* __restrict__ vx, const float* __restrict__ Wv1,
                      const float* __restrict__ bv1, float* __restrict__ v) {
    __shared__ float cat[512];
    int b = blockIdx.x, t = threadIdx.x;
    float cnt = fmaxf((float)counts[b], 1.0f);
    cat[t] = sums[b * 256 + t] / cnt;
    cat[t + 256] = vx[b * 256 + t];
    __syncthreads();
    float a = 0.f;
    #pragma unroll 8
    for (int k = 0; k < 512; ++k) a = fmaf(cat[k], Wv1[k * 256 + t], a);
    a += bv1[t];
    v[b * 256 + t] = ssilu_f(a);
}

// ---- virtual-node MLP layer 2: vx_new = ssilu(v @ Wv2 + bv2) ----
__global__ void vmlp2(const float* __restrict__ v, const float* __restrict__ Wv2,
                      const float* __restrict__ bv2, float* __restrict__ out) {
    __shared__ float rowv[256];
    int b = blockIdx.x, t = threadIdx.x;
    rowv[t] = v[b * 256 + t];
    __syncthreads();
    float a = 0.f;
    #pragma unroll 8
    for (int k = 0; k < 256; ++k) a = fmaf(rowv[k], Wv2[k * 256 + t], a);
    a += bv2[t];
    out[b * 256 + t] = ssilu_f(a);
}

extern "C" void kernel_launch(void* const* d_in, const int* in_sizes, int n_in,
                              void* d_out, int out_size, void* d_ws, size_t ws_size,
                              hipStream_t stream) {
    const float* x   = (const float*)d_in[0];
    const int*   batch = (const int*)d_in[1];
    const float* vx  = (const float*)d_in[2];
    const float* Wn1 = (const float*)d_in[3];
    const float* bn1 = (const float*)d_in[4];
    const float* Wn2 = (const float*)d_in[5];
    const float* bn2 = (const float*)d_in[6];
    const float* Wv1 = (const float*)d_in[7];
    const float* bv1 = (const float*)d_in[8];
    const float* Wv2 = (const float*)d_in[9];
    const float* bv2 = (const float*)d_in[10];

    float* hout = (float*)d_out;
    float* vout = hout + (size_t)N_ROWS * 256;   // also reused as v-scratch

    // ws layout — total 393,472 B
    char* ws = (char*)d_ws;
    unsigned short* wnt1x  = (unsigned short*)(ws);           // 256*256*2 = 131072
    unsigned short* wnt2   = (unsigned short*)(ws + 131072);  // 131072
    float*          vc     = (float*)(ws + 262144);           // 64*256*4  = 65536
    float*          sums   = (float*)(ws + 327680);           // 65536
    int*            counts = (int*)(ws + 393216);             // 256

    cvt_transpose<<<256, 256, 0, stream>>>(Wn1, wnt1x);   // x-half of Wn1 (rows 0..255)
    cvt_transpose<<<256, 256, 0, stream>>>(Wn2, wnt2);
    vc_kernel<<<NGRAPH, 256, 0, stream>>>(vx, Wn1, bn1, vc);
    prep_kernel<<<NGRAPH, 256, 0, stream>>>(batch, sums, counts);
    node_kernel<<<NTILES, 256, 0, stream>>>(x, batch, wnt1x, vc, wnt2, bn2, hout, sums);
    vmlp1<<<NGRAPH, 256, 0, stream>>>(sums, counts, vx, Wv1, bv1, vout);
    vmlp2<<<NGRAPH, 256, 0, stream>>>(vout, Wv2, bv2, vout);
}